// Round 8
// baseline (76.058 us; speedup 1.0000x reference)
//
#include <hip/hip_runtime.h>
#include <stdint.h>

#define ROT(x, r) (((x) << (r)) | ((x) >> (32 - (r))))

#define TF_BODY(k0, k1, x0, x1, o0, o1)                                  \
  {                                                                      \
    uint32_t ks2 = (k0) ^ (k1) ^ 0x1BD11BDAu;                            \
    x0 += (k0); x1 += (k1);                                              \
    x0 += x1; x1 = ROT(x1,13); x1 ^= x0;                                 \
    x0 += x1; x1 = ROT(x1,15); x1 ^= x0;                                 \
    x0 += x1; x1 = ROT(x1,26); x1 ^= x0;                                 \
    x0 += x1; x1 = ROT(x1, 6); x1 ^= x0;                                 \
    x0 += (k1); x1 += ks2 + 1u;                                          \
    x0 += x1; x1 = ROT(x1,17); x1 ^= x0;                                 \
    x0 += x1; x1 = ROT(x1,29); x1 ^= x0;                                 \
    x0 += x1; x1 = ROT(x1,16); x1 ^= x0;                                 \
    x0 += x1; x1 = ROT(x1,24); x1 ^= x0;                                 \
    x0 += ks2; x1 += (k0) + 2u;                                          \
    x0 += x1; x1 = ROT(x1,13); x1 ^= x0;                                 \
    x0 += x1; x1 = ROT(x1,15); x1 ^= x0;                                 \
    x0 += x1; x1 = ROT(x1,26); x1 ^= x0;                                 \
    x0 += x1; x1 = ROT(x1, 6); x1 ^= x0;                                 \
    x0 += (k0); x1 += (k1) + 3u;                                         \
    x0 += x1; x1 = ROT(x1,17); x1 ^= x0;                                 \
    x0 += x1; x1 = ROT(x1,29); x1 ^= x0;                                 \
    x0 += x1; x1 = ROT(x1,16); x1 ^= x0;                                 \
    x0 += x1; x1 = ROT(x1,24); x1 ^= x0;                                 \
    x0 += (k1); x1 += ks2 + 4u;                                          \
    x0 += x1; x1 = ROT(x1,13); x1 ^= x0;                                 \
    x0 += x1; x1 = ROT(x1,15); x1 ^= x0;                                 \
    x0 += x1; x1 = ROT(x1,26); x1 ^= x0;                                 \
    x0 += x1; x1 = ROT(x1, 6); x1 ^= x0;                                 \
    o0 = x0 + ks2;                                                       \
    o1 = x1 + (k0) + 5u;                                                 \
  }

__device__ __forceinline__ void tf_block(uint32_t k0, uint32_t k1,
                                         uint32_t x0, uint32_t x1,
                                         uint32_t& o0, uint32_t& o1) {
  TF_BODY(k0, k1, x0, x1, o0, o1)
}

// XLA's EmitTanh f32: clamp to [-9,9], rational poly (unfused mul/add),
// |x| < 0.0004 -> passthrough.
__device__ inline float xla_tanh_f32(float x) {
#pragma clang fp contract(off)
  float ax = fabsf(x);
  float xc = fminf(fmaxf(x, -9.0f), 9.0f);
  float x2 = xc * xc;
  float num = -2.76076847742355e-16f;
  num = x2 * num + 2.00018790482477e-13f;
  num = x2 * num + -8.60467152213735e-11f;
  num = x2 * num + 5.12229709037114e-08f;
  num = x2 * num + 1.48572235717979e-05f;
  num = x2 * num + 6.37261928875436e-04f;
  num = x2 * num + 4.89352455891786e-03f;
  num = xc * num;
  float den = 1.19825839466702e-06f;
  den = x2 * den + 1.18534705686654e-04f;
  den = x2 * den + 2.26843463243900e-03f;
  den = x2 * den + 4.89352518554385e-03f;
  float res = num / den;   // IEEE f32 division (no fast-math)
  return (ax < 0.0004f) ? x : res;
}

// XLA LogisticExpander: logistic(x) = 0.5 + 0.5 * tanh(0.5 * x)
__device__ inline float sigmoid_xla(float s) {
#pragma clang fp contract(off)
  float t = xla_tanh_f32(0.5f * s);
  return 0.5f + 0.5f * t;
}

// Kernel A: prob[n] = sigmoid_xla(5f*w[n]) + per-block f64 partial sum (256 blocks)
__global__ void prob_sum_kernel(const float* __restrict__ w, float* __restrict__ prob,
                                double* __restrict__ partial) {
#pragma clang fp contract(off)
  __shared__ double sm[256];
  int n = blockIdx.x * 256 + threadIdx.x;
  float s = 5.0f * w[n];
  float p = sigmoid_xla(s);
  prob[n] = p;
  sm[threadIdx.x] = (double)p;
  __syncthreads();
  for (int off = 128; off > 0; off >>= 1) {
    if (threadIdx.x < off) sm[threadIdx.x] += sm[threadIdx.x + off];
    __syncthreads();
  }
  if (threadIdx.x == 0) partial[blockIdx.x] = sm[0];
}

// Kernel B: final f64 reduce (1 block) -> r/beta/le scalars
__global__ void final_kernel(const double* __restrict__ partial, float* __restrict__ sc) {
#pragma clang fp contract(off)
  __shared__ double sm[256];
  sm[threadIdx.x] = partial[threadIdx.x];
  __syncthreads();
  for (int off = 128; off > 0; off >>= 1) {
    if (threadIdx.x < off) sm[threadIdx.x] += sm[threadIdx.x + off];
    __syncthreads();
  }
  if (threadIdx.x == 0) {
    double S = sm[0];                         // exact row sum (f64)
    float xbar = (float)(S / 65536.0);        // exact /2^16, then single f32 RN
    float r    = 0.125f / xbar;
    float beta = 0.875f / (1.0f - xbar);
    sc[0] = r; sc[1] = beta; sc[2] = (r <= 1.0f) ? 1.0f : 0.0f;
  }
}

// Kernel C: integer thresholds, one column per thread (256 blocks).
// u = m*2^-23 exactly (m = bits>>9), so (u <= resc) <=> (m <= floor(resc*2^23)).
__global__ void thresh_kernel(const float* __restrict__ prob,
                              const float* __restrict__ sc,
                              uint32_t* __restrict__ thresh) {
#pragma clang fp contract(off)
  int n = blockIdx.x * 256 + threadIdx.x;
  float r = sc[0], beta = sc[1], le = sc[2];
  float p = prob[n];
  float resc = (le != 0.0f) ? (p * r) : (1.0f - (1.0f - p) * beta);
  double f = floor((double)resc * 8388608.0);     // exact
  if (f > 8388607.0) f = 8388607.0;               // all-pass clamp (m < 2^23)
  thresh[n] = (uint32_t)f;
}

// Kernel D: 32 elements/thread (4 grid-stride iterations x 8), thresh hoisted
// (stride 2^23 elems == 0 mod 65536 -> column base invariant), 8 independent
// threefry chains per iteration, float4 x2 loads/stores, integer compare.
__global__ __launch_bounds__(256) void mask_kernel(
    const float4* __restrict__ x4, const uint32_t* __restrict__ thresh,
    float4* __restrict__ out4, uint32_t sk0, uint32_t sk1) {
  const uint32_t T = 4096u * 256u;                 // thread-slots per iteration
  uint32_t g0 = blockIdx.x * 256u + threadIdx.x;   // [0, 2^20)
  uint32_t n0 = (g0 * 8u) & 65535u;                // column base (iter-invariant)
  const uint4* tp = reinterpret_cast<const uint4*>(thresh + n0);
  uint4 Ta = tp[0];
  uint4 Tb = tp[1];
#pragma unroll 2
  for (uint32_t it = 0; it < 4; ++it) {
    uint32_t g  = g0 + it * T;                     // [0, 2^22)
    uint32_t i0 = g * 8u;                          // flat element base
    float4 xa = x4[2u * g];
    float4 xb = x4[2u * g + 1u];
    uint32_t m[8];
#pragma unroll
    for (int j = 0; j < 8; ++j) {
      uint32_t o0, o1;
      tf_block(sk0, sk1, 0u, i0 + (uint32_t)j, o0, o1);
      m[j] = (o0 ^ o1) >> 9;
    }
    float4 oa, ob;
    oa.x = (m[0] <= Ta.x) ? xa.x : 0.0f;
    oa.y = (m[1] <= Ta.y) ? xa.y : 0.0f;
    oa.z = (m[2] <= Ta.z) ? xa.z : 0.0f;
    oa.w = (m[3] <= Ta.w) ? xa.w : 0.0f;
    ob.x = (m[4] <= Tb.x) ? xb.x : 0.0f;
    ob.y = (m[5] <= Tb.y) ? xb.y : 0.0f;
    ob.z = (m[6] <= Tb.z) ? xb.z : 0.0f;
    ob.w = (m[7] <= Tb.w) ? xb.w : 0.0f;
    out4[2u * g]      = oa;
    out4[2u * g + 1u] = ob;
  }
}

extern "C" void kernel_launch(void* const* d_in, const int* in_sizes, int n_in,
                              void* d_out, int out_size, void* d_ws, size_t ws_size,
                              hipStream_t stream) {
  const float* x;
  const float* w;
  if (in_sizes[0] == 65536) { w = (const float*)d_in[0]; x = (const float*)d_in[1]; }
  else                      { x = (const float*)d_in[0]; w = (const float*)d_in[1]; }
  float* out = (float*)d_out;                     // f32 output, 2^25 elements

  float*    prob    = (float*)d_ws;                          // 256 KiB
  uint32_t* thresh  = (uint32_t*)((char*)d_ws + 65536 * 4);  // 256 KiB
  double*   partial = (double*)((char*)d_ws + 2 * 65536 * 4);// 2 KiB
  float*    sc      = (float*)((char*)d_ws + 2 * 65536 * 4 + 2048);

  // Partitionable split of key(42): subkey = block (0,1) under key (0,42)
  uint32_t s0, s1;
  {
    uint32_t k0 = 0u, k1 = 42u, x0 = 0u, x1 = 1u, o0, o1;
    TF_BODY(k0, k1, x0, x1, o0, o1)
    s0 = o0; s1 = o1;
  }

  prob_sum_kernel<<<256, 256, 0, stream>>>(w, prob, partial);
  final_kernel<<<1, 256, 0, stream>>>(partial, sc);
  thresh_kernel<<<256, 256, 0, stream>>>(prob, sc, thresh);
  mask_kernel<<<4096, 256, 0, stream>>>((const float4*)x, thresh, (float4*)out, s0, s1);
}

// Round 9
// 74.121 us; speedup vs baseline: 1.0261x; 1.0261x over previous
//
#include <hip/hip_runtime.h>
#include <stdint.h>

#define ROT(x, r) (((x) << (r)) | ((x) >> (32 - (r))))

#define TF_BODY(k0, k1, x0, x1, o0, o1)                                  \
  {                                                                      \
    uint32_t ks2 = (k0) ^ (k1) ^ 0x1BD11BDAu;                            \
    x0 += (k0); x1 += (k1);                                              \
    x0 += x1; x1 = ROT(x1,13); x1 ^= x0;                                 \
    x0 += x1; x1 = ROT(x1,15); x1 ^= x0;                                 \
    x0 += x1; x1 = ROT(x1,26); x1 ^= x0;                                 \
    x0 += x1; x1 = ROT(x1, 6); x1 ^= x0;                                 \
    x0 += (k1); x1 += ks2 + 1u;                                          \
    x0 += x1; x1 = ROT(x1,17); x1 ^= x0;                                 \
    x0 += x1; x1 = ROT(x1,29); x1 ^= x0;                                 \
    x0 += x1; x1 = ROT(x1,16); x1 ^= x0;                                 \
    x0 += x1; x1 = ROT(x1,24); x1 ^= x0;                                 \
    x0 += ks2; x1 += (k0) + 2u;                                          \
    x0 += x1; x1 = ROT(x1,13); x1 ^= x0;                                 \
    x0 += x1; x1 = ROT(x1,15); x1 ^= x0;                                 \
    x0 += x1; x1 = ROT(x1,26); x1 ^= x0;                                 \
    x0 += x1; x1 = ROT(x1, 6); x1 ^= x0;                                 \
    x0 += (k0); x1 += (k1) + 3u;                                         \
    x0 += x1; x1 = ROT(x1,17); x1 ^= x0;                                 \
    x0 += x1; x1 = ROT(x1,29); x1 ^= x0;                                 \
    x0 += x1; x1 = ROT(x1,16); x1 ^= x0;                                 \
    x0 += x1; x1 = ROT(x1,24); x1 ^= x0;                                 \
    x0 += (k1); x1 += ks2 + 4u;                                          \
    x0 += x1; x1 = ROT(x1,13); x1 ^= x0;                                 \
    x0 += x1; x1 = ROT(x1,15); x1 ^= x0;                                 \
    x0 += x1; x1 = ROT(x1,26); x1 ^= x0;                                 \
    x0 += x1; x1 = ROT(x1, 6); x1 ^= x0;                                 \
    o0 = x0 + ks2;                                                       \
    o1 = x1 + (k0) + 5u;                                                 \
  }

// One ARX round applied to two independent chains, op-interleaved (ILP=2).
#define R2(a0,a1,b0,b1,rc)                                               \
    a0 += a1;        b0 += b1;                                           \
    a1 = ROT(a1,rc); b1 = ROT(b1,rc);                                    \
    a1 ^= a0;        b1 ^= b0;

// Two threefry2x32 blocks (x0=0, x1=ia / x1=ib) under key (k0,k1),
// returning folded bits (o0^o1) per block. Bit-exact TF_BODY op order,
// chains interleaved pairwise for in-wave ILP.
__device__ __forceinline__ void tf2_fold(uint32_t k0, uint32_t k1, uint32_t ks2,
                                         uint32_t ia, uint32_t ib,
                                         uint32_t& fa, uint32_t& fb) {
  // x0 += k0 with x0=0 -> constant k0; x1 += k1
  uint32_t a0 = k0, a1 = ia + k1;
  uint32_t b0 = k0, b1 = ib + k1;
  R2(a0,a1,b0,b1,13) R2(a0,a1,b0,b1,15) R2(a0,a1,b0,b1,26) R2(a0,a1,b0,b1, 6)
  a0 += k1;        b0 += k1;        a1 += ks2 + 1u;  b1 += ks2 + 1u;
  R2(a0,a1,b0,b1,17) R2(a0,a1,b0,b1,29) R2(a0,a1,b0,b1,16) R2(a0,a1,b0,b1,24)
  a0 += ks2;       b0 += ks2;       a1 += k0 + 2u;   b1 += k0 + 2u;
  R2(a0,a1,b0,b1,13) R2(a0,a1,b0,b1,15) R2(a0,a1,b0,b1,26) R2(a0,a1,b0,b1, 6)
  a0 += k0;        b0 += k0;        a1 += k1 + 3u;   b1 += k1 + 3u;
  R2(a0,a1,b0,b1,17) R2(a0,a1,b0,b1,29) R2(a0,a1,b0,b1,16) R2(a0,a1,b0,b1,24)
  a0 += k1;        b0 += k1;        a1 += ks2 + 4u;  b1 += ks2 + 4u;
  R2(a0,a1,b0,b1,13) R2(a0,a1,b0,b1,15) R2(a0,a1,b0,b1,26) R2(a0,a1,b0,b1, 6)
  fa = (a0 + ks2) ^ (a1 + k0 + 5u);
  fb = (b0 + ks2) ^ (b1 + k0 + 5u);
}

// XLA's EmitTanh f32: clamp to [-9,9], rational poly (unfused mul/add),
// |x| < 0.0004 -> passthrough.
__device__ inline float xla_tanh_f32(float x) {
#pragma clang fp contract(off)
  float ax = fabsf(x);
  float xc = fminf(fmaxf(x, -9.0f), 9.0f);
  float x2 = xc * xc;
  float num = -2.76076847742355e-16f;
  num = x2 * num + 2.00018790482477e-13f;
  num = x2 * num + -8.60467152213735e-11f;
  num = x2 * num + 5.12229709037114e-08f;
  num = x2 * num + 1.48572235717979e-05f;
  num = x2 * num + 6.37261928875436e-04f;
  num = x2 * num + 4.89352455891786e-03f;
  num = xc * num;
  float den = 1.19825839466702e-06f;
  den = x2 * den + 1.18534705686654e-04f;
  den = x2 * den + 2.26843463243900e-03f;
  den = x2 * den + 4.89352518554385e-03f;
  float res = num / den;   // IEEE f32 division (no fast-math)
  return (ax < 0.0004f) ? x : res;
}

// XLA LogisticExpander: logistic(x) = 0.5 + 0.5 * tanh(0.5 * x)
__device__ inline float sigmoid_xla(float s) {
#pragma clang fp contract(off)
  float t = xla_tanh_f32(0.5f * s);
  return 0.5f + 0.5f * t;
}

// Kernel A: prob[n] = sigmoid_xla(5f*w[n]) + per-block f64 partial sum (256 blocks)
__global__ void prob_sum_kernel(const float* __restrict__ w, float* __restrict__ prob,
                                double* __restrict__ partial) {
#pragma clang fp contract(off)
  __shared__ double sm[256];
  int n = blockIdx.x * 256 + threadIdx.x;
  float s = 5.0f * w[n];
  float p = sigmoid_xla(s);
  prob[n] = p;
  sm[threadIdx.x] = (double)p;
  __syncthreads();
  for (int off = 128; off > 0; off >>= 1) {
    if (threadIdx.x < off) sm[threadIdx.x] += sm[threadIdx.x + off];
    __syncthreads();
  }
  if (threadIdx.x == 0) partial[blockIdx.x] = sm[0];
}

// Kernel B: final f64 reduce (1 block) -> r/beta/le scalars
__global__ void final_kernel(const double* __restrict__ partial, float* __restrict__ sc) {
#pragma clang fp contract(off)
  __shared__ double sm[256];
  sm[threadIdx.x] = partial[threadIdx.x];
  __syncthreads();
  for (int off = 128; off > 0; off >>= 1) {
    if (threadIdx.x < off) sm[threadIdx.x] += sm[threadIdx.x + off];
    __syncthreads();
  }
  if (threadIdx.x == 0) {
    double S = sm[0];                         // exact row sum (f64)
    float xbar = (float)(S / 65536.0);        // exact /2^16, then single f32 RN
    float r    = 0.125f / xbar;
    float beta = 0.875f / (1.0f - xbar);
    sc[0] = r; sc[1] = beta; sc[2] = (r <= 1.0f) ? 1.0f : 0.0f;
  }
}

// Kernel C: PRE-SHIFTED integer thresholds, one column per thread.
// u = m*2^-23 (m = bits>>9); (u <= resc) <=> (m <= floor(resc*2^23))
//   <=> (bits <= (floor(resc*2^23)<<9 | 0x1FF)). Clamp -> 0xFFFFFFFF = all-pass.
__global__ void thresh_kernel(const float* __restrict__ prob,
                              const float* __restrict__ sc,
                              uint32_t* __restrict__ thresh) {
#pragma clang fp contract(off)
  int n = blockIdx.x * 256 + threadIdx.x;
  float r = sc[0], beta = sc[1], le = sc[2];
  float p = prob[n];
  float resc = (le != 0.0f) ? (p * r) : (1.0f - (1.0f - p) * beta);
  double f = floor((double)resc * 8388608.0);     // exact
  uint32_t tq;
  if (f > 8388607.0)    tq = 0xFFFFFFFFu;         // all-pass (m < 2^23 always)
  else if (f < 0.0)     tq = 0u;                  // (resc>=0 here; defensive)
  else                  tq = ((uint32_t)f << 9) | 0x1FFu;
  thresh[n] = tq;
}

// Kernel D: 8 elements/thread, 4 x 2-way interleaved threefry (tf2_fold),
// float4 x2 loads/stores, pre-shifted integer compare.
__global__ __launch_bounds__(256) void mask_kernel(
    const float4* __restrict__ x4, const uint32_t* __restrict__ thresh,
    float4* __restrict__ out4, uint32_t sk0, uint32_t sk1) {
  uint32_t ks2 = sk0 ^ sk1 ^ 0x1BD11BDAu;
  uint32_t t  = blockIdx.x * 256u + threadIdx.x;   // [0, 2^22)
  uint32_t i0 = t * 8u;                            // flat element base
  uint32_t n0 = i0 & 65535u;                       // column base (mult of 8)
  const uint4* tp = reinterpret_cast<const uint4*>(thresh + n0);
  uint4 Ta = tp[0];
  uint4 Tb = tp[1];
  float4 xa = x4[2u * t];
  float4 xb = x4[2u * t + 1u];
  uint32_t f0, f1, f2, f3, f4, f5, f6, f7;
  tf2_fold(sk0, sk1, ks2, i0 + 0u, i0 + 1u, f0, f1);
  tf2_fold(sk0, sk1, ks2, i0 + 2u, i0 + 3u, f2, f3);
  tf2_fold(sk0, sk1, ks2, i0 + 4u, i0 + 5u, f4, f5);
  tf2_fold(sk0, sk1, ks2, i0 + 6u, i0 + 7u, f6, f7);
  float4 oa, ob;
  oa.x = (f0 <= Ta.x) ? xa.x : 0.0f;
  oa.y = (f1 <= Ta.y) ? xa.y : 0.0f;
  oa.z = (f2 <= Ta.z) ? xa.z : 0.0f;
  oa.w = (f3 <= Ta.w) ? xa.w : 0.0f;
  ob.x = (f4 <= Tb.x) ? xb.x : 0.0f;
  ob.y = (f5 <= Tb.y) ? xb.y : 0.0f;
  ob.z = (f6 <= Tb.z) ? xb.z : 0.0f;
  ob.w = (f7 <= Tb.w) ? xb.w : 0.0f;
  out4[2u * t]      = oa;
  out4[2u * t + 1u] = ob;
}

extern "C" void kernel_launch(void* const* d_in, const int* in_sizes, int n_in,
                              void* d_out, int out_size, void* d_ws, size_t ws_size,
                              hipStream_t stream) {
  const float* x;
  const float* w;
  if (in_sizes[0] == 65536) { w = (const float*)d_in[0]; x = (const float*)d_in[1]; }
  else                      { x = (const float*)d_in[0]; w = (const float*)d_in[1]; }
  float* out = (float*)d_out;                     // f32 output, 2^25 elements

  float*    prob    = (float*)d_ws;                          // 256 KiB
  uint32_t* thresh  = (uint32_t*)((char*)d_ws + 65536 * 4);  // 256 KiB
  double*   partial = (double*)((char*)d_ws + 2 * 65536 * 4);// 2 KiB
  float*    sc      = (float*)((char*)d_ws + 2 * 65536 * 4 + 2048);

  // Partitionable split of key(42): subkey = block (0,1) under key (0,42)
  uint32_t s0, s1;
  {
    uint32_t k0 = 0u, k1 = 42u, x0 = 0u, x1 = 1u, o0, o1;
    TF_BODY(k0, k1, x0, x1, o0, o1)
    s0 = o0; s1 = o1;
  }

  prob_sum_kernel<<<256, 256, 0, stream>>>(w, prob, partial);
  final_kernel<<<1, 256, 0, stream>>>(partial, sc);
  thresh_kernel<<<256, 256, 0, stream>>>(prob, sc, thresh);
  mask_kernel<<<16384, 256, 0, stream>>>((const float4*)x, thresh, (float4*)out, s0, s1);
}

// Round 10
// 73.819 us; speedup vs baseline: 1.0303x; 1.0041x over previous
//
#include <hip/hip_runtime.h>
#include <stdint.h>

// Single-instruction rotate: clang lowers to fshl -> v_alignbit_b32 on gfx950.
#define ROTL(x, r) __builtin_rotateleft32((x), (r))

#define TF_BODY(k0, k1, x0, x1, o0, o1)                                  \
  {                                                                      \
    uint32_t ks2 = (k0) ^ (k1) ^ 0x1BD11BDAu;                            \
    x0 += (k0); x1 += (k1);                                              \
    x0 += x1; x1 = ROTL(x1,13); x1 ^= x0;                                \
    x0 += x1; x1 = ROTL(x1,15); x1 ^= x0;                                \
    x0 += x1; x1 = ROTL(x1,26); x1 ^= x0;                                \
    x0 += x1; x1 = ROTL(x1, 6); x1 ^= x0;                                \
    x0 += (k1); x1 += ks2 + 1u;                                          \
    x0 += x1; x1 = ROTL(x1,17); x1 ^= x0;                                \
    x0 += x1; x1 = ROTL(x1,29); x1 ^= x0;                                \
    x0 += x1; x1 = ROTL(x1,16); x1 ^= x0;                                \
    x0 += x1; x1 = ROTL(x1,24); x1 ^= x0;                                \
    x0 += ks2; x1 += (k0) + 2u;                                          \
    x0 += x1; x1 = ROTL(x1,13); x1 ^= x0;                                \
    x0 += x1; x1 = ROTL(x1,15); x1 ^= x0;                                \
    x0 += x1; x1 = ROTL(x1,26); x1 ^= x0;                                \
    x0 += x1; x1 = ROTL(x1, 6); x1 ^= x0;                                \
    x0 += (k0); x1 += (k1) + 3u;                                         \
    x0 += x1; x1 = ROTL(x1,17); x1 ^= x0;                                \
    x0 += x1; x1 = ROTL(x1,29); x1 ^= x0;                                \
    x0 += x1; x1 = ROTL(x1,16); x1 ^= x0;                                \
    x0 += x1; x1 = ROTL(x1,24); x1 ^= x0;                                \
    x0 += (k1); x1 += ks2 + 4u;                                          \
    x0 += x1; x1 = ROTL(x1,13); x1 ^= x0;                                \
    x0 += x1; x1 = ROTL(x1,15); x1 ^= x0;                                \
    x0 += x1; x1 = ROTL(x1,26); x1 ^= x0;                                \
    x0 += x1; x1 = ROTL(x1, 6); x1 ^= x0;                                \
    o0 = x0 + ks2;                                                       \
    o1 = x1 + (k0) + 5u;                                                 \
  }

// One ARX round applied to two independent chains, op-interleaved (ILP=2).
#define R2(a0,a1,b0,b1,rc)                                               \
    a0 += a1;         b0 += b1;                                          \
    a1 = ROTL(a1,rc); b1 = ROTL(b1,rc);                                  \
    a1 ^= a0;         b1 ^= b0;

// Two threefry2x32 blocks (x0=0, x1=ia / x1=ib) under key (k0,k1),
// returning folded bits (o0^o1) per block. Bit-exact TF_BODY op order.
__device__ __forceinline__ void tf2_fold(uint32_t k0, uint32_t k1, uint32_t ks2,
                                         uint32_t ia, uint32_t ib,
                                         uint32_t& fa, uint32_t& fb) {
  uint32_t a0 = k0, a1 = ia + k1;   // x0 += k0 with x0=0 -> constant
  uint32_t b0 = k0, b1 = ib + k1;
  R2(a0,a1,b0,b1,13) R2(a0,a1,b0,b1,15) R2(a0,a1,b0,b1,26) R2(a0,a1,b0,b1, 6)
  a0 += k1;        b0 += k1;        a1 += ks2 + 1u;  b1 += ks2 + 1u;
  R2(a0,a1,b0,b1,17) R2(a0,a1,b0,b1,29) R2(a0,a1,b0,b1,16) R2(a0,a1,b0,b1,24)
  a0 += ks2;       b0 += ks2;       a1 += k0 + 2u;   b1 += k0 + 2u;
  R2(a0,a1,b0,b1,13) R2(a0,a1,b0,b1,15) R2(a0,a1,b0,b1,26) R2(a0,a1,b0,b1, 6)
  a0 += k0;        b0 += k0;        a1 += k1 + 3u;   b1 += k1 + 3u;
  R2(a0,a1,b0,b1,17) R2(a0,a1,b0,b1,29) R2(a0,a1,b0,b1,16) R2(a0,a1,b0,b1,24)
  a0 += k1;        b0 += k1;        a1 += ks2 + 4u;  b1 += ks2 + 4u;
  R2(a0,a1,b0,b1,13) R2(a0,a1,b0,b1,15) R2(a0,a1,b0,b1,26) R2(a0,a1,b0,b1, 6)
  fa = (a0 + ks2) ^ (a1 + k0 + 5u);
  fb = (b0 + ks2) ^ (b1 + k0 + 5u);
}

// XLA's EmitTanh f32: clamp to [-9,9], rational poly (unfused mul/add),
// |x| < 0.0004 -> passthrough.
__device__ inline float xla_tanh_f32(float x) {
#pragma clang fp contract(off)
  float ax = fabsf(x);
  float xc = fminf(fmaxf(x, -9.0f), 9.0f);
  float x2 = xc * xc;
  float num = -2.76076847742355e-16f;
  num = x2 * num + 2.00018790482477e-13f;
  num = x2 * num + -8.60467152213735e-11f;
  num = x2 * num + 5.12229709037114e-08f;
  num = x2 * num + 1.48572235717979e-05f;
  num = x2 * num + 6.37261928875436e-04f;
  num = x2 * num + 4.89352455891786e-03f;
  num = xc * num;
  float den = 1.19825839466702e-06f;
  den = x2 * den + 1.18534705686654e-04f;
  den = x2 * den + 2.26843463243900e-03f;
  den = x2 * den + 4.89352518554385e-03f;
  float res = num / den;   // IEEE f32 division (no fast-math)
  return (ax < 0.0004f) ? x : res;
}

// XLA LogisticExpander: logistic(x) = 0.5 + 0.5 * tanh(0.5 * x)
__device__ inline float sigmoid_xla(float s) {
#pragma clang fp contract(off)
  float t = xla_tanh_f32(0.5f * s);
  return 0.5f + 0.5f * t;
}

// Kernel A: prob[n] = sigmoid_xla(5f*w[n]) + per-block f64 partial sum (256 blocks)
__global__ void prob_sum_kernel(const float* __restrict__ w, float* __restrict__ prob,
                                double* __restrict__ partial) {
#pragma clang fp contract(off)
  __shared__ double sm[256];
  int n = blockIdx.x * 256 + threadIdx.x;
  float s = 5.0f * w[n];
  float p = sigmoid_xla(s);
  prob[n] = p;
  sm[threadIdx.x] = (double)p;
  __syncthreads();
  for (int off = 128; off > 0; off >>= 1) {
    if (threadIdx.x < off) sm[threadIdx.x] += sm[threadIdx.x + off];
    __syncthreads();
  }
  if (threadIdx.x == 0) partial[blockIdx.x] = sm[0];
}

// Kernel B: final f64 reduce (1 block) -> r/beta/le scalars
__global__ void final_kernel(const double* __restrict__ partial, float* __restrict__ sc) {
#pragma clang fp contract(off)
  __shared__ double sm[256];
  sm[threadIdx.x] = partial[threadIdx.x];
  __syncthreads();
  for (int off = 128; off > 0; off >>= 1) {
    if (threadIdx.x < off) sm[threadIdx.x] += sm[threadIdx.x + off];
    __syncthreads();
  }
  if (threadIdx.x == 0) {
    double S = sm[0];                         // exact row sum (f64)
    float xbar = (float)(S / 65536.0);        // exact /2^16, then single f32 RN
    float r    = 0.125f / xbar;
    float beta = 0.875f / (1.0f - xbar);
    sc[0] = r; sc[1] = beta; sc[2] = (r <= 1.0f) ? 1.0f : 0.0f;
  }
}

// Kernel C: PRE-SHIFTED integer thresholds, one column per thread.
// u = m*2^-23 (m = bits>>9); (u <= resc) <=> (bits <= (floor(resc*2^23)<<9 | 0x1FF)).
__global__ void thresh_kernel(const float* __restrict__ prob,
                              const float* __restrict__ sc,
                              uint32_t* __restrict__ thresh) {
#pragma clang fp contract(off)
  int n = blockIdx.x * 256 + threadIdx.x;
  float r = sc[0], beta = sc[1], le = sc[2];
  float p = prob[n];
  float resc = (le != 0.0f) ? (p * r) : (1.0f - (1.0f - p) * beta);
  double f = floor((double)resc * 8388608.0);     // exact
  uint32_t tq;
  if (f > 8388607.0)    tq = 0xFFFFFFFFu;         // all-pass (m < 2^23 always)
  else if (f < 0.0)     tq = 0u;                  // defensive
  else                  tq = ((uint32_t)f << 9) | 0x1FFu;
  thresh[n] = tq;
}

// Kernel D: 8 elements/thread, 4 x 2-way interleaved threefry (tf2_fold),
// float4 x2 loads/stores, pre-shifted integer compare.
__global__ __launch_bounds__(256) void mask_kernel(
    const float4* __restrict__ x4, const uint32_t* __restrict__ thresh,
    float4* __restrict__ out4, uint32_t sk0, uint32_t sk1) {
  uint32_t ks2 = sk0 ^ sk1 ^ 0x1BD11BDAu;
  uint32_t t  = blockIdx.x * 256u + threadIdx.x;   // [0, 2^22)
  uint32_t i0 = t * 8u;                            // flat element base
  uint32_t n0 = i0 & 65535u;                       // column base (mult of 8)
  const uint4* tp = reinterpret_cast<const uint4*>(thresh + n0);
  uint4 Ta = tp[0];
  uint4 Tb = tp[1];
  float4 xa = x4[2u * t];
  float4 xb = x4[2u * t + 1u];
  uint32_t f0, f1, f2, f3, f4, f5, f6, f7;
  tf2_fold(sk0, sk1, ks2, i0 + 0u, i0 + 1u, f0, f1);
  tf2_fold(sk0, sk1, ks2, i0 + 2u, i0 + 3u, f2, f3);
  tf2_fold(sk0, sk1, ks2, i0 + 4u, i0 + 5u, f4, f5);
  tf2_fold(sk0, sk1, ks2, i0 + 6u, i0 + 7u, f6, f7);
  float4 oa, ob;
  oa.x = (f0 <= Ta.x) ? xa.x : 0.0f;
  oa.y = (f1 <= Ta.y) ? xa.y : 0.0f;
  oa.z = (f2 <= Ta.z) ? xa.z : 0.0f;
  oa.w = (f3 <= Ta.w) ? xa.w : 0.0f;
  ob.x = (f4 <= Tb.x) ? xb.x : 0.0f;
  ob.y = (f5 <= Tb.y) ? xb.y : 0.0f;
  ob.z = (f6 <= Tb.z) ? xb.z : 0.0f;
  ob.w = (f7 <= Tb.w) ? xb.w : 0.0f;
  out4[2u * t]      = oa;
  out4[2u * t + 1u] = ob;
}

extern "C" void kernel_launch(void* const* d_in, const int* in_sizes, int n_in,
                              void* d_out, int out_size, void* d_ws, size_t ws_size,
                              hipStream_t stream) {
  const float* x;
  const float* w;
  if (in_sizes[0] == 65536) { w = (const float*)d_in[0]; x = (const float*)d_in[1]; }
  else                      { x = (const float*)d_in[0]; w = (const float*)d_in[1]; }
  float* out = (float*)d_out;                     // f32 output, 2^25 elements

  float*    prob    = (float*)d_ws;                          // 256 KiB
  uint32_t* thresh  = (uint32_t*)((char*)d_ws + 65536 * 4);  // 256 KiB
  double*   partial = (double*)((char*)d_ws + 2 * 65536 * 4);// 2 KiB
  float*    sc      = (float*)((char*)d_ws + 2 * 65536 * 4 + 2048);

  // Partitionable split of key(42): subkey = block (0,1) under key (0,42)
  uint32_t s0, s1;
  {
    uint32_t k0 = 0u, k1 = 42u, x0 = 0u, x1 = 1u, o0, o1;
    TF_BODY(k0, k1, x0, x1, o0, o1)
    s0 = o0; s1 = o1;
  }

  prob_sum_kernel<<<256, 256, 0, stream>>>(w, prob, partial);
  final_kernel<<<1, 256, 0, stream>>>(partial, sc);
  thresh_kernel<<<256, 256, 0, stream>>>(prob, sc, thresh);
  mask_kernel<<<16384, 256, 0, stream>>>((const float4*)x, thresh, (float4*)out, s0, s1);
}

// Round 11
// 73.273 us; speedup vs baseline: 1.0380x; 1.0075x over previous
//
#include <hip/hip_runtime.h>
#include <stdint.h>

// Single-instruction rotate (lowered to v_alignbit_b32 on gfx950).
#define ROTL(x, r) __builtin_rotateleft32((x), (r))

#define TF_BODY(k0, k1, x0, x1, o0, o1)                                  \
  {                                                                      \
    uint32_t ks2 = (k0) ^ (k1) ^ 0x1BD11BDAu;                            \
    x0 += (k0); x1 += (k1);                                              \
    x0 += x1; x1 = ROTL(x1,13); x1 ^= x0;                                \
    x0 += x1; x1 = ROTL(x1,15); x1 ^= x0;                                \
    x0 += x1; x1 = ROTL(x1,26); x1 ^= x0;                                \
    x0 += x1; x1 = ROTL(x1, 6); x1 ^= x0;                                \
    x0 += (k1); x1 += ks2 + 1u;                                          \
    x0 += x1; x1 = ROTL(x1,17); x1 ^= x0;                                \
    x0 += x1; x1 = ROTL(x1,29); x1 ^= x0;                                \
    x0 += x1; x1 = ROTL(x1,16); x1 ^= x0;                                \
    x0 += x1; x1 = ROTL(x1,24); x1 ^= x0;                                \
    x0 += ks2; x1 += (k0) + 2u;                                          \
    x0 += x1; x1 = ROTL(x1,13); x1 ^= x0;                                \
    x0 += x1; x1 = ROTL(x1,15); x1 ^= x0;                                \
    x0 += x1; x1 = ROTL(x1,26); x1 ^= x0;                                \
    x0 += x1; x1 = ROTL(x1, 6); x1 ^= x0;                                \
    x0 += (k0); x1 += (k1) + 3u;                                         \
    x0 += x1; x1 = ROTL(x1,17); x1 ^= x0;                                \
    x0 += x1; x1 = ROTL(x1,29); x1 ^= x0;                                \
    x0 += x1; x1 = ROTL(x1,16); x1 ^= x0;                                \
    x0 += x1; x1 = ROTL(x1,24); x1 ^= x0;                                \
    x0 += (k1); x1 += ks2 + 4u;                                          \
    x0 += x1; x1 = ROTL(x1,13); x1 ^= x0;                                \
    x0 += x1; x1 = ROTL(x1,15); x1 ^= x0;                                \
    x0 += x1; x1 = ROTL(x1,26); x1 ^= x0;                                \
    x0 += x1; x1 = ROTL(x1, 6); x1 ^= x0;                                \
    o0 = x0 + ks2;                                                       \
    o1 = x1 + (k0) + 5u;                                                 \
  }

// One ARX round applied to two independent chains, op-interleaved (ILP=2).
#define R2(a0,a1,b0,b1,rc)                                               \
    a0 += a1;         b0 += b1;                                          \
    a1 = ROTL(a1,rc); b1 = ROTL(b1,rc);                                  \
    a1 ^= a0;         b1 ^= b0;

// Two threefry2x32 blocks (x0=0, x1=ia/ib) under key (k0,k1), folded output.
// Round 1 folded into init (x0=0 -> a0 = k0 + a1i), bit-exact vs TF_BODY.
__device__ __forceinline__ void tf2_fold(uint32_t k0, uint32_t k1, uint32_t ks2,
                                         uint32_t ia, uint32_t ib,
                                         uint32_t& fa, uint32_t& fb) {
  uint32_t a1i = ia + k1,            b1i = ib + k1;
  uint32_t a0  = k0 + a1i,           b0  = k0 + b1i;
  uint32_t a1  = ROTL(a1i,13) ^ a0,  b1  = ROTL(b1i,13) ^ b0;
  R2(a0,a1,b0,b1,15) R2(a0,a1,b0,b1,26) R2(a0,a1,b0,b1, 6)
  a0 += k1;        b0 += k1;        a1 += ks2 + 1u;  b1 += ks2 + 1u;
  R2(a0,a1,b0,b1,17) R2(a0,a1,b0,b1,29) R2(a0,a1,b0,b1,16) R2(a0,a1,b0,b1,24)
  a0 += ks2;       b0 += ks2;       a1 += k0 + 2u;   b1 += k0 + 2u;
  R2(a0,a1,b0,b1,13) R2(a0,a1,b0,b1,15) R2(a0,a1,b0,b1,26) R2(a0,a1,b0,b1, 6)
  a0 += k0;        b0 += k0;        a1 += k1 + 3u;   b1 += k1 + 3u;
  R2(a0,a1,b0,b1,17) R2(a0,a1,b0,b1,29) R2(a0,a1,b0,b1,16) R2(a0,a1,b0,b1,24)
  a0 += k1;        b0 += k1;        a1 += ks2 + 4u;  b1 += ks2 + 4u;
  R2(a0,a1,b0,b1,13) R2(a0,a1,b0,b1,15) R2(a0,a1,b0,b1,26) R2(a0,a1,b0,b1, 6)
  fa = (a0 + ks2) ^ (a1 + k0 + 5u);
  fb = (b0 + ks2) ^ (b1 + k0 + 5u);
}

// XLA's EmitTanh f32: clamp to [-9,9], rational poly (unfused mul/add),
// |x| < 0.0004 -> passthrough.
__device__ inline float xla_tanh_f32(float x) {
#pragma clang fp contract(off)
  float ax = fabsf(x);
  float xc = fminf(fmaxf(x, -9.0f), 9.0f);
  float x2 = xc * xc;
  float num = -2.76076847742355e-16f;
  num = x2 * num + 2.00018790482477e-13f;
  num = x2 * num + -8.60467152213735e-11f;
  num = x2 * num + 5.12229709037114e-08f;
  num = x2 * num + 1.48572235717979e-05f;
  num = x2 * num + 6.37261928875436e-04f;
  num = x2 * num + 4.89352455891786e-03f;
  num = xc * num;
  float den = 1.19825839466702e-06f;
  den = x2 * den + 1.18534705686654e-04f;
  den = x2 * den + 2.26843463243900e-03f;
  den = x2 * den + 4.89352518554385e-03f;
  float res = num / den;   // IEEE f32 division (no fast-math)
  return (ax < 0.0004f) ? x : res;
}

// XLA LogisticExpander: logistic(x) = 0.5 + 0.5 * tanh(0.5 * x)
__device__ inline float sigmoid_xla(float s) {
#pragma clang fp contract(off)
  float t = xla_tanh_f32(0.5f * s);
  return 0.5f + 0.5f * t;
}

// Kernel A: prob[n] = sigmoid_xla(5f*w[n]) + per-block f64 partial sum (256 blocks)
__global__ void prob_sum_kernel(const float* __restrict__ w, float* __restrict__ prob,
                                double* __restrict__ partial) {
#pragma clang fp contract(off)
  __shared__ double sm[256];
  int n = blockIdx.x * 256 + threadIdx.x;
  float s = 5.0f * w[n];
  float p = sigmoid_xla(s);
  prob[n] = p;
  sm[threadIdx.x] = (double)p;
  __syncthreads();
  for (int off = 128; off > 0; off >>= 1) {
    if (threadIdx.x < off) sm[threadIdx.x] += sm[threadIdx.x + off];
    __syncthreads();
  }
  if (threadIdx.x == 0) partial[blockIdx.x] = sm[0];
}

// Kernel B (FUSED final+thresh): each of 256 blocks re-reduces the 256 f64
// partials (2 KB, L2-hot; redundant but cheap) -> xbar -> r/beta/le, then
// writes its 256 pre-shifted integer thresholds.
// u = m*2^-23 (m = bits>>9); (u <= resc) <=> (bits <= (floor(resc*2^23)<<9 | 0x1FF)).
__global__ void thresh_fused_kernel(const float* __restrict__ prob,
                                    const double* __restrict__ partial,
                                    uint32_t* __restrict__ thresh) {
#pragma clang fp contract(off)
  __shared__ double sm[256];
  sm[threadIdx.x] = partial[threadIdx.x];
  __syncthreads();
  for (int off = 128; off > 0; off >>= 1) {
    if (threadIdx.x < off) sm[threadIdx.x] += sm[threadIdx.x + off];
    __syncthreads();
  }
  double S = sm[0];                          // exact row sum (f64), synced
  float xbar = (float)(S / 65536.0);         // exact /2^16, then single f32 RN
  float r    = 0.125f / xbar;
  float beta = 0.875f / (1.0f - xbar);
  float le   = (r <= 1.0f) ? 1.0f : 0.0f;
  int n = blockIdx.x * 256 + threadIdx.x;
  float p = prob[n];
  float resc = (le != 0.0f) ? (p * r) : (1.0f - (1.0f - p) * beta);
  double f = floor((double)resc * 8388608.0);     // exact
  uint32_t tq;
  if (f > 8388607.0)    tq = 0xFFFFFFFFu;         // all-pass (m < 2^23 always)
  else if (f < 0.0)     tq = 0u;                  // defensive
  else                  tq = ((uint32_t)f << 9) | 0x1FFu;
  thresh[n] = tq;
}

// Kernel C: 8 elements/thread, 4 x 2-way interleaved threefry (tf2_fold),
// float4 x2 loads/stores, pre-shifted integer compare.
__global__ __launch_bounds__(256) void mask_kernel(
    const float4* __restrict__ x4, const uint32_t* __restrict__ thresh,
    float4* __restrict__ out4, uint32_t sk0, uint32_t sk1) {
  uint32_t ks2 = sk0 ^ sk1 ^ 0x1BD11BDAu;
  uint32_t t  = blockIdx.x * 256u + threadIdx.x;   // [0, 2^22)
  uint32_t i0 = t * 8u;                            // flat element base
  uint32_t n0 = i0 & 65535u;                       // column base (mult of 8)
  const uint4* tp = reinterpret_cast<const uint4*>(thresh + n0);
  uint4 Ta = tp[0];
  uint4 Tb = tp[1];
  float4 xa = x4[2u * t];
  float4 xb = x4[2u * t + 1u];
  uint32_t f0, f1, f2, f3, f4, f5, f6, f7;
  tf2_fold(sk0, sk1, ks2, i0 + 0u, i0 + 1u, f0, f1);
  tf2_fold(sk0, sk1, ks2, i0 + 2u, i0 + 3u, f2, f3);
  tf2_fold(sk0, sk1, ks2, i0 + 4u, i0 + 5u, f4, f5);
  tf2_fold(sk0, sk1, ks2, i0 + 6u, i0 + 7u, f6, f7);
  float4 oa, ob;
  oa.x = (f0 <= Ta.x) ? xa.x : 0.0f;
  oa.y = (f1 <= Ta.y) ? xa.y : 0.0f;
  oa.z = (f2 <= Ta.z) ? xa.z : 0.0f;
  oa.w = (f3 <= Ta.w) ? xa.w : 0.0f;
  ob.x = (f4 <= Tb.x) ? xb.x : 0.0f;
  ob.y = (f5 <= Tb.y) ? xb.y : 0.0f;
  ob.z = (f6 <= Tb.z) ? xb.z : 0.0f;
  ob.w = (f7 <= Tb.w) ? xb.w : 0.0f;
  out4[2u * t]      = oa;
  out4[2u * t + 1u] = ob;
}

extern "C" void kernel_launch(void* const* d_in, const int* in_sizes, int n_in,
                              void* d_out, int out_size, void* d_ws, size_t ws_size,
                              hipStream_t stream) {
  const float* x;
  const float* w;
  if (in_sizes[0] == 65536) { w = (const float*)d_in[0]; x = (const float*)d_in[1]; }
  else                      { x = (const float*)d_in[0]; w = (const float*)d_in[1]; }
  float* out = (float*)d_out;                     // f32 output, 2^25 elements

  float*    prob    = (float*)d_ws;                          // 256 KiB
  uint32_t* thresh  = (uint32_t*)((char*)d_ws + 65536 * 4);  // 256 KiB
  double*   partial = (double*)((char*)d_ws + 2 * 65536 * 4);// 2 KiB

  // Partitionable split of key(42): subkey = block (0,1) under key (0,42)
  uint32_t s0, s1;
  {
    uint32_t k0 = 0u, k1 = 42u, x0 = 0u, x1 = 1u, o0, o1;
    TF_BODY(k0, k1, x0, x1, o0, o1)
    s0 = o0; s1 = o1;
  }

  prob_sum_kernel<<<256, 256, 0, stream>>>(w, prob, partial);
  thresh_fused_kernel<<<256, 256, 0, stream>>>(prob, partial, thresh);
  mask_kernel<<<16384, 256, 0, stream>>>((const float4*)x, thresh, (float4*)out, s0, s1);
}